// Round 13
// baseline (409.323 us; speedup 1.0000x reference)
//
#include <hip/hip_runtime.h>
#include <hip/hip_fp8.h>

// ---------------------------------------------------------------------------
// GAT 3-layer classifier. CSR build -> per layer: mfma-gemm(+attn coefs) ->
// aggregate -> pool/cls.
// R17: as/ad folded into GEMM via precomputed w_asd; dbuf one-barrier GEMM.
// R19: cooperative mega-kernels DEAD (1 block/CU -> 171us prep).
// R22: fp8 e4m3 h-table layers 1-2 (agg 67.5->48us, absmax unchanged).
// R23: NPW=4 occupancy collapse; REVERTED. R24: pk-FMA agg 48->43.4us.
// R25 (340.4us champion): pk-FMA + memset folded into prep. 13 dispatches.
//      Dispatch overhead ~4us each (R24 +1=+4.3, R25 -2=-7.4 concordant).
// R26 (this): two sync-free dispatch merges (11 total):
//   (a) scan_partial+scan_blocks -> one kernel via PARALLEL aggregate
//       lookback (agg[b] published with release store right after local
//       scan; wave0 lane l polls agg[l] independently -- no chaining, one
//       poll round; NB=49 blocks all co-resident). rowptr is now ABSOLUTE:
//       bs[] chunk-offset gathers deleted from scatter + all aggregates.
//   (b) pool+classify via last-block-done ticket (threadfence idiom);
//       `done` lives in the prep-zeroed region so graph replay re-arms it.
// ---------------------------------------------------------------------------

typedef __attribute__((ext_vector_type(8))) __bf16 bf16x8;
typedef __attribute__((ext_vector_type(4))) float f32x4;
typedef __attribute__((ext_vector_type(2))) float f32x2;
typedef __attribute__((ext_vector_type(8))) unsigned short u16x8;

#define LOG2E 1.44269504f

static __device__ __forceinline__ unsigned short f2bf(float f) {
    unsigned u = __float_as_uint(f);
    unsigned r = (u + 0x7fffu + ((u >> 16) & 1u)) >> 16;
    return (unsigned short)r;
}
static __device__ __forceinline__ float bf2f(unsigned short s) {
    return __uint_as_float(((unsigned)s) << 16);
}

// ---- fp8 e4m3 (OCP) encode/decode, HW cvt when available ----
#if __has_builtin(__builtin_amdgcn_cvt_pk_fp8_f32)
static __device__ __forceinline__ unsigned char f2fp8(float v) {
    return (unsigned char)(__builtin_amdgcn_cvt_pk_fp8_f32(v, v, 0, false) & 0xff);
}
#else
static __device__ __forceinline__ unsigned char f2fp8(float v) {
    return (unsigned char)__hip_cvt_float_to_fp8(v, __HIP_SATFINITE, __HIP_E4M3);
}
#endif

#if __has_builtin(__builtin_amdgcn_cvt_pk_f32_fp8)
template <bool HI>
static __device__ __forceinline__ f32x2 fp8pair(unsigned int w) {
    return __builtin_amdgcn_cvt_pk_f32_fp8(w, HI);   // HI literal per instantiation
}
#else
static __device__ __forceinline__ float fp8one(unsigned char x) {
    __half_raw hr = __hip_cvt_fp8_to_halfraw((__hip_fp8_storage_t)x, __HIP_E4M3);
    return __half2float(*(const __half*)&hr);
}
template <bool HI>
static __device__ __forceinline__ f32x2 fp8pair(unsigned int w) {
    unsigned int s = HI ? (w >> 16) : w;
    f32x2 r;
    r[0] = fp8one((unsigned char)(s & 0xff));
    r[1] = fp8one((unsigned char)((s >> 8) & 0xff));
    return r;
}
#endif

static __device__ __forceinline__ void g2lds16(const unsigned short* g,
                                               unsigned short* l) {
    __builtin_amdgcn_global_load_lds(
        (const __attribute__((address_space(1))) unsigned int*)g,
        (__attribute__((address_space(3))) unsigned int*)l, 16, 0, 0);
}

// ============================ CSR build ====================================
__global__ void count_edges(const int* __restrict__ ei, int* __restrict__ deg,
                            int* __restrict__ epos, int E) {
    int i = blockIdx.x * blockDim.x + threadIdx.x;
    if (i >= E) return;
    int dst = ei[E + i];
    epos[i] = atomicAdd(&deg[dst], 1);
}

// Merged scan: per-1024-chunk exclusive scan of (deg[i]+1) with parallel
// aggregate-lookback across chunks.  aggst[b] (init -1 by prep) holds chunk
// b's total once published.  rowptr is written ABSOLUTE; last chunk writes
// rowptr[N] = grand total.
__global__ __launch_bounds__(256) void scan_fused(const int* __restrict__ deg,
                                                  int* __restrict__ rowptr,
                                                  int* __restrict__ aggst,
                                                  int N, int NB) {
    int b = blockIdx.x;
    int t = threadIdx.x;
    int lane = t & 63, wv = t >> 6;
    int base = b * 1024 + t * 4;
    int v[4];
#pragma unroll
    for (int j = 0; j < 4; ++j) v[j] = (base + j < N) ? deg[base + j] + 1 : 0;
    int local = v[0] + v[1] + v[2] + v[3];
    int x = local;
#pragma unroll
    for (int off = 1; off < 64; off <<= 1) {
        int y = __shfl_up(x, off);
        if (lane >= off) x += y;
    }
    __shared__ int wsum[4];
    __shared__ int prevSh;
    if (lane == 63) wsum[wv] = x;
    __syncthreads();
    int tot = wsum[0] + wsum[1] + wsum[2] + wsum[3];
    if (t == 0)   // publish this chunk's aggregate immediately (release)
        __hip_atomic_store(&aggst[b], tot, __ATOMIC_RELEASE, __HIP_MEMORY_SCOPE_AGENT);
    int woff = 0;
    for (int i = 0; i < wv; ++i) woff += wsum[i];
    // wave 0: parallel lookback — lane l polls predecessor l's aggregate.
    if (wv == 0) {
        int pref = 0;
        for (int b0 = 0; b0 < b; b0 += 64) {
            int idx = b0 + lane;
            int va = 0;
            if (idx < b) {
                do {
                    va = __hip_atomic_load(&aggst[idx], __ATOMIC_ACQUIRE,
                                           __HIP_MEMORY_SCOPE_AGENT);
                } while (va < 0);
            }
#pragma unroll
            for (int off = 32; off >= 1; off >>= 1) va += __shfl_xor(va, off);
            pref += va;    // butterfly leaves the sum in all lanes
        }
        if (lane == 0) {
            prevSh = pref;
            if (b == NB - 1) rowptr[N] = pref + tot;
        }
    }
    __syncthreads();
    int run = prevSh + woff + x - local;
#pragma unroll
    for (int j = 0; j < 4; ++j) {
        if (base + j < N) rowptr[base + j] = run;
        run += v[j];
    }
}

// atomic-free scatter (rowptr absolute).
__global__ void scatter_edges(const int* __restrict__ ei, const int* __restrict__ rowptr,
                              const int* __restrict__ deg, const int* __restrict__ epos,
                              int* __restrict__ srcs, int E, int N) {
    int i = blockIdx.x * blockDim.x + threadIdx.x;
    int tot = E + N;
    if (i >= tot) return;
    if (i < E) {
        int dst = ei[E + i];
        srcs[rowptr[dst] + epos[i]] = ei[i];
    } else {
        int d = i - E;
        srcs[rowptr[d] + deg[d]] = d;
    }
}

// ================= fused weight casts + attn weights + zeroing =============
// Also zeroes deg[0..N), sums/counts/done (zsums[0..zn)), and arms the scan
// lookback slots aggst[0..NB) = -1.  Runs before count_edges each launch.
// w_asd[p][k] = sum_c W[k, h*C+c] * a[h][c]  (p<H: a_src, H<=p<2H: a_dst,
// p>=2H: 0).  16 rows x K bf16 per layer, k-contiguous (Bt layout).
__global__ void prep_weights(const float* __restrict__ W1, unsigned short* __restrict__ Wt1,
                             const float* __restrict__ W2, unsigned short* __restrict__ Wt2,
                             const float* __restrict__ W3, unsigned short* __restrict__ Wt3,
                             const float* __restrict__ as1, const float* __restrict__ ad1,
                             const float* __restrict__ as2, const float* __restrict__ ad2,
                             const float* __restrict__ as3, const float* __restrict__ ad3,
                             unsigned short* __restrict__ wasd1,
                             unsigned short* __restrict__ wasd2,
                             unsigned short* __restrict__ wasd3,
                             int* __restrict__ deg, float* __restrict__ zsums,
                             int* __restrict__ aggst,
                             int N, int zn, int NB,
                             int n1, int n2, int n3, int F_IN, int HC, int C) {
    int i = blockIdx.x * blockDim.x + threadIdx.x;
    if (i < N) deg[i] = 0;
    if (i < zn) zsums[i] = 0.f;
    if (i < NB) aggst[i] = -1;
    if (i < n1) {  // Wt1: [HC][F_IN]
        int n = i / F_IN, k = i - n * F_IN;
        Wt1[i] = f2bf(W1[(size_t)k * HC + n]);
        return;
    }
    i -= n1;
    if (i < n2) {  // Wt2: [HC][HC]
        int n = i / HC, k = i - n * HC;
        Wt2[i] = f2bf(W2[(size_t)k * HC + n]);
        return;
    }
    i -= n2;
    if (i < n3) {  // Wt3: [C][HC]
        int n = i / HC, k = i - n * HC;
        Wt3[i] = f2bf(W3[(size_t)k * C + n]);
        return;
    }
    i -= n3;
    if (i < 16 * 128) {               // wasd1: K=128, H=4, C=64
        int p = i >> 7, k = i & 127;
        float v = 0.f;
        if (p < 8) {
            const float* a = (p < 4) ? as1 : ad1;
            int hh = p & 3;
            for (int c = 0; c < 64; ++c)
                v += W1[(size_t)k * 256 + hh * 64 + c] * a[hh * 64 + c];
        }
        wasd1[i] = f2bf(v);
        return;
    }
    i -= 16 * 128;
    if (i < 16 * 256) {               // wasd2: K=256, H=4, C=64
        int p = i >> 8, k = i & 255;
        float v = 0.f;
        if (p < 8) {
            const float* a = (p < 4) ? as2 : ad2;
            int hh = p & 3;
            for (int c = 0; c < 64; ++c)
                v += W2[(size_t)k * 256 + hh * 64 + c] * a[hh * 64 + c];
        }
        wasd2[i] = f2bf(v);
        return;
    }
    i -= 16 * 256;
    if (i < 16 * 256) {               // wasd3: K=256, H=1, C=64
        int p = i >> 8, k = i & 255;
        float v = 0.f;
        if (p < 2) {
            const float* a = p ? ad3 : as3;
            for (int c = 0; c < 64; ++c)
                v += W3[(size_t)k * 64 + c] * a[c];
        }
        wasd3[i] = f2bf(v);
    }
}

// ============================ MFMA GEMM + fused attn coefs =================
// C[M,BN] = A[M,K] @ Bt[BN,K](bf16)^T, BN == N exactly (grid.x=1).
// WAVES_N=4: BM=64, BN=256 (wave==head).  WAVES_N=1: BM=256, BN=64.
// Double-buffered LDS, one barrier per K-step (R17).  as/ad via one extra
// MFMA per A-frag against the precomputed w_asd fragment; stored from the
// accumulator with LOG2E fold.  C8: C stored as fp8 e4m3 (byte/lane).
#define BK 32

template <bool AF32, int WAVES_N, bool C8>
__global__ __launch_bounds__(256) void gemm_bf16(const void* __restrict__ Av,
                                                 const unsigned short* __restrict__ Bt,
                                                 const unsigned short* __restrict__ Wasd,
                                                 void* __restrict__ Cv,
                                                 float* __restrict__ as_o,
                                                 float* __restrict__ ad_o,
                                                 int M, int N, int K, int H) {
    constexpr int BMt = (4 / WAVES_N) * 64;
    constexpr int BNt = WAVES_N * 64;
    constexpr int ASLOTS = BMt * 4;               // 16B slots for the A tile
    constexpr int ROUNDS = (BMt + BNt) / 64;      // g2lds rounds (non-AF32)
    constexpr bool ASD_ALL = (WAVES_N == 1);
    __shared__ unsigned short As[2][BMt * BK];
    __shared__ unsigned short Bs[2][BNt * BK];
    __shared__ unsigned short Ws[2][16 * BK];
    int t = threadIdx.x;
    int bm = blockIdx.y * BMt;
    int wave = t >> 6, lane = t & 63;
    int wm = (wave / WAVES_N) * 64, wn = (wave % WAVES_N) * 64;
    int quad = lane >> 4, mr = lane & 15;

    f32x4 zero = {0.f, 0.f, 0.f, 0.f};
    f32x4 acc[4][4];
#pragma unroll
    for (int i = 0; i < 4; ++i)
#pragma unroll
        for (int j = 0; j < 4; ++j) acc[i][j] = zero;
    f32x4 acc4[4];
#pragma unroll
    for (int i = 0; i < 4; ++i) acc4[i] = zero;

    int sw = quad ^ ((mr >> 1) & 3);
    int aoff[4], boff[4];
#pragma unroll
    for (int i = 0; i < 4; ++i) {
        aoff[i] = (wm + i * 16 + mr) * BK + sw * 8;
        boff[i] = (wn + i * 16 + mr) * BK + sw * 8;
    }

    auto stage_ab = [&](int bsel, int kk) {
        const unsigned short* Ab = (const unsigned short*)Av;
#pragma unroll
        for (int r = 0; r < ROUNDS; ++r) {
            int slotw = r * 256 + wave * 64;      // wave-uniform slot base
            int slot = slotw + lane;
            if (slotw < ASLOTS) {
                int row = slot >> 2;
                int sg = (slot & 3) ^ ((row >> 1) & 3);
                int gra = bm + row;
                if (gra < M)
                    g2lds16(&Ab[(size_t)gra * K + kk + sg * 8], &As[bsel][slotw * 8]);
            } else {
                int bslot = slot - ASLOTS;
                int row = bslot >> 2;
                int sg = (bslot & 3) ^ ((row >> 1) & 3);
                g2lds16(&Bt[(size_t)row * K + kk + sg * 8], &Bs[bsel][(slotw - ASLOTS) * 8]);
            }
        }
        if (wave == 0)
            g2lds16(&Wasd[(size_t)(lane >> 2) * K + kk + (lane & 3) * 8], &Ws[bsel][0]);
    };
    auto stage_b_af32 = [&](int bsel, int kk) {
#pragma unroll
        for (int r = 0; r < BNt / 64; ++r) {
            int slotw = r * 256 + wave * 64;
            int bslot = slotw + lane;
            int row = bslot >> 2;
            int sg = (bslot & 3) ^ ((row >> 1) & 3);
            g2lds16(&Bt[(size_t)row * K + kk + sg * 8], &Bs[bsel][slotw * 8]);
        }
        if (wave == 0)
            g2lds16(&Wasd[(size_t)(lane >> 2) * K + kk + (lane & 3) * 8], &Ws[bsel][0]);
    };
    auto loadA_f32 = [&](int kk, float4& lo, float4& hi) {
        int slot = t, row = slot >> 2;
        int sg = (slot & 3) ^ ((row >> 1) & 3);
        int gra = bm + row;
        lo = make_float4(0.f, 0.f, 0.f, 0.f); hi = lo;
        if (gra < M) {
            const float* Af = (const float*)Av;
            lo = *(const float4*)&Af[(size_t)gra * K + kk + sg * 8];
            hi = *(const float4*)&Af[(size_t)gra * K + kk + sg * 8 + 4];
        }
    };
    auto writeA = [&](int bsel, float4 lo, float4 hi) {
        int slot = t;
        *(ushort4*)&As[bsel][slot * 8]     = make_ushort4(f2bf(lo.x), f2bf(lo.y), f2bf(lo.z), f2bf(lo.w));
        *(ushort4*)&As[bsel][slot * 8 + 4] = make_ushort4(f2bf(hi.x), f2bf(hi.y), f2bf(hi.z), f2bf(hi.w));
    };

    const int nt = K / BK;
    int cur = 0;

    if (AF32) {
        float4 l0, h0;
        loadA_f32(0, l0, h0);
        writeA(0, l0, h0);
        stage_b_af32(0, 0);
    } else {
        stage_ab(0, 0);
    }
    __syncthreads();

    for (int ts = 0; ts < nt; ++ts) {
        int nxt = cur ^ 1;
        bool more = (ts + 1 < nt);
        float4 plo, phi;
        if (more) {
            if (AF32) {
                loadA_f32((ts + 1) * BK, plo, phi);      // issue early
                stage_b_af32(nxt, (ts + 1) * BK);
            } else {
                stage_ab(nxt, (ts + 1) * BK);
            }
        }
        bf16x8 af[4], bfr[4];
#pragma unroll
        for (int i = 0; i < 4; ++i) {
            af[i]  = *(bf16x8*)&As[cur][aoff[i]];
            bfr[i] = *(bf16x8*)&Bs[cur][boff[i]];
        }
#pragma unroll
        for (int i = 0; i < 4; ++i)
#pragma unroll
            for (int j = 0; j < 4; ++j)
                acc[i][j] = __builtin_amdgcn_mfma_f32_16x16x32_bf16(af[i], bfr[j], acc[i][j], 0, 0, 0);
        if (ASD_ALL || wave == 0) {
            bf16x8 wsf = *(bf16x8*)&Ws[cur][mr * BK + quad * 8];
#pragma unroll
            for (int i = 0; i < 4; ++i)
                acc4[i] = __builtin_amdgcn_mfma_f32_16x16x32_bf16(af[i], wsf, acc4[i], 0, 0, 0);
        }
        if (more && AF32) writeA(nxt, plo, phi);         // write late
        __syncthreads();
        cur = nxt;
    }

    // as/ad store: D col=mr is coefficient index p (p<H: as, else ad)
    if ((ASD_ALL || wave == 0) && mr < 2 * H) {
#pragma unroll
        for (int i = 0; i < 4; ++i)
#pragma unroll
            for (int r = 0; r < 4; ++r) {
                int grow = bm + wm + i * 16 + quad * 4 + r;
                if (grow >= M) continue;
                float v = acc4[i][r] * LOG2E;
                if (mr < H) as_o[(size_t)grow * H + mr] = v;
                else        ad_o[(size_t)grow * H + (mr - H)] = v;
            }
    }

    // C store: C/D layout col=lane&15, row=quad*4+reg
#pragma unroll
    for (int i = 0; i < 4; ++i) {
#pragma unroll
        for (int r = 0; r < 4; ++r) {
            int grow = bm + wm + i * 16 + quad * 4 + r;
            if (grow >= M) continue;
#pragma unroll
            for (int j = 0; j < 4; ++j) {
                int gcol = wn + j * 16 + mr;
                if constexpr (C8) {
                    ((unsigned char*)Cv)[(size_t)grow * N + gcol] = f2fp8(acc[i][j][r]);
                } else {
                    ((unsigned short*)Cv)[(size_t)grow * N + gcol] = f2bf(acc[i][j][r]);
                }
            }
        }
    }
}

// ============================ aggregation ==================================
// Single-pass unnormalized softmax: out = sum(exp(e)*h) / (sum(exp(e))+eps).
// as/ad pre-scaled by log2(e) -> exp2; leaky = fmax(e, 0.2e).
// IN8 VPL=8: NPW=2, uint2 8B/lane; f32x2 accumulate -> v_pk_fma_f32.
// rowptr is ABSOLUTE (R26) — no chunk-offset gathers.
template <int H, int NPW, int VPL, bool OUTF32, bool IN8>
__global__ __launch_bounds__(256) void gat_aggregate(const void* __restrict__ hbuf_v,
                                                     const float* __restrict__ as_i,
                                                     const float* __restrict__ ad_i,
                                                     const int* __restrict__ rowptr,
                                                     const int* __restrict__ srcs,
                                                     const float* __restrict__ bias,
                                                     void* __restrict__ out_v, int N) {
    constexpr int LPN = 64 / NPW;        // lanes per node
    constexpr int HC = LPN * VPL;        // channels per node
    int wid = (blockIdx.x * blockDim.x + threadIdx.x) >> 6;
    int lane = threadIdx.x & 63;
    int sub = lane / LPN;                // which node within the wave
    int li  = lane % LPN;                // lane within node
    int node = wid * NPW + sub;
    if (node >= N) return;
    int row = rowptr[node];
    int end = rowptr[node + 1];
    int len = end - row;
    const int hd_lane = (li * VPL) >> 6; // head = channel/64

    float advh = ad_i[(size_t)node * H + hd_lane];

    float acc[VPL] __attribute__((aligned(16)));
#pragma unroll
    for (int j = 0; j < VPL; ++j) acc[j] = 0.f;
    float l = 0.f;

    const int U = 8;
    for (int base = 0; base < len; base += U) {
        int s[U];
        float cf[U];
#pragma unroll
        for (int u = 0; u < U; ++u) {
            int idx = base + u;
            int ii = row + ((idx < len) ? idx : (len - 1));
            s[u] = srcs[ii];
        }
#pragma unroll
        for (int u = 0; u < U; ++u) cf[u] = as_i[(size_t)s[u] * H + hd_lane];
        if constexpr (IN8 && VPL == 8) {
            // fp8 path: 8 channels = 8 bytes per edge-lane (uint2);
            // f32x2 accumulate -> v_pk_fma_f32
            const unsigned char* hb = (const unsigned char*)hbuf_v;
            uint2 r[U];
#pragma unroll
            for (int u = 0; u < U; ++u)
                r[u] = *(const uint2*)&hb[(size_t)s[u] * HC + li * VPL];
            f32x2* acc2 = (f32x2*)acc;
#pragma unroll
            for (int u = 0; u < U; ++u) {
                float e = cf[u] + advh;
                e = fmaxf(e, 0.2f * e);
                float wgt = (base + u < len) ? exp2f(e) : 0.f;
                l += wgt;
                f32x2 w2 = {wgt, wgt};
                acc2[0] += w2 * fp8pair<false>(r[u].x);
                acc2[1] += w2 * fp8pair<true >(r[u].x);
                acc2[2] += w2 * fp8pair<false>(r[u].y);
                acc2[3] += w2 * fp8pair<true >(r[u].y);
            }
        } else if constexpr (VPL == 8) {
            const unsigned short* hb = (const unsigned short*)hbuf_v;
            u16x8 r[U];
#pragma unroll
            for (int u = 0; u < U; ++u)
                r[u] = *(const u16x8*)&hb[(size_t)s[u] * HC + li * 8];
#pragma unroll
            for (int u = 0; u < U; ++u) {
                float e = cf[u] + advh;
                e = fmaxf(e, 0.2f * e);
                float wgt = (base + u < len) ? exp2f(e) : 0.f;
                l += wgt;
#pragma unroll
                for (int j = 0; j < 8; ++j) acc[j] += wgt * bf2f(r[u][j]);
            }
        } else {
            const unsigned short* hb = (const unsigned short*)hbuf_v;
            ushort4 r[U];
#pragma unroll
            for (int u = 0; u < U; ++u)
                r[u] = *(const ushort4*)&hb[(size_t)s[u] * HC + li * 4];
#pragma unroll
            for (int u = 0; u < U; ++u) {
                float e = cf[u] + advh;
                e = fmaxf(e, 0.2f * e);
                float wgt = (base + u < len) ? exp2f(e) : 0.f;
                l += wgt;
                acc[0] += wgt * bf2f(r[u].x);
                acc[1] += wgt * bf2f(r[u].y);
                acc[2] += wgt * bf2f(r[u].z);
                acc[3] += wgt * bf2f(r[u].w);
            }
        }
    }

    float inv_l = 1.f / (l + 1e-16f);
    float vals[VPL];
#pragma unroll
    for (int j = 0; j < VPL; ++j) {
        float v = acc[j] * inv_l + bias[li * VPL + j];
        vals[j] = (v > 0.f) ? v : (__expf(v) - 1.f);
    }
    if constexpr (OUTF32) {
        float* out = (float*)out_v;
        if constexpr (VPL == 4) {
            float4 o = make_float4(vals[0], vals[1], vals[2], vals[3]);
            *(float4*)&out[(size_t)node * HC + li * 4] = o;
        } else {
#pragma unroll
            for (int j = 0; j < VPL; ++j)
                out[(size_t)node * HC + li * VPL + j] = vals[j];
        }
    } else {
        unsigned short* out = (unsigned short*)out_v;
        if constexpr (VPL == 8) {
            u16x8 o;
#pragma unroll
            for (int j = 0; j < 8; ++j) o[j] = f2bf(vals[j]);
            *(u16x8*)&out[(size_t)node * HC + li * 8] = o;
        } else {
            ushort4 o;
            o.x = f2bf(vals[0]); o.y = f2bf(vals[1]);
            o.z = f2bf(vals[2]); o.w = f2bf(vals[3]);
            *(ushort4*)&out[(size_t)node * HC + li * 4] = o;
        }
    }
}

// ====================== pool + classify (last-block) =======================
#define POOL_CHUNK 128
__global__ __launch_bounds__(256) void pool_classify(const float* __restrict__ hf,
                                                     const int* __restrict__ batch,
                                                     float* __restrict__ sums,
                                                     float* __restrict__ counts,
                                                     const float* __restrict__ Wc,
                                                     const float* __restrict__ bc,
                                                     float* __restrict__ out,
                                                     int* __restrict__ done,
                                                     int N, int NC, int NPB) {
    int t = threadIdx.x;
    int c = t & 63, sub = t >> 6;
    int start = blockIdx.x * POOL_CHUNK;
    int end = min(start + POOL_CHUNK, N);
    float acc = 0.f, cnt = 0.f;
    int cur = -1;
    for (int n = start + sub; n < end; n += 4) {
        int g = batch[n];
        if (g != cur) {
            if (cur >= 0) {
                atomicAdd(&sums[cur * 64 + c], acc);
                if (c == 0) atomicAdd(&counts[cur], cnt);
            }
            cur = g; acc = 0.f; cnt = 0.f;
        }
        acc += hf[(size_t)n * 64 + c];
        cnt += 1.f;
    }
    if (cur >= 0) {
        atomicAdd(&sums[cur * 64 + c], acc);
        if (c == 0) atomicAdd(&counts[cur], cnt);
    }

    // last-block-done: the final block to finish pooling runs classification.
    __threadfence();
    __syncthreads();
    __shared__ int ticket;
    if (t == 0) ticket = atomicAdd(done, 1);
    __syncthreads();
    if (ticket != NPB - 1) return;
    __threadfence();   // acquire: all other blocks' atomics now visible

    __shared__ float p[64];
    for (int g = 0; g < 64; ++g) {
        __syncthreads();
        if (t < 64) {
            float cnt2 = fmaxf(counts[g], 1.0f);
            p[t] = sums[g * 64 + t] / cnt2;
        }
        __syncthreads();
        if (t < NC) {
            float a = bc[t];
            for (int cc = 0; cc < 64; ++cc) a += p[cc] * Wc[cc * NC + t];
            out[g * NC + t] = a;
        }
    }
}

static inline size_t align_up(size_t x, size_t a) { return (x + a - 1) / a * a; }

extern "C" void kernel_launch(void* const* d_in, const int* in_sizes, int n_in,
                              void* d_out, int out_size, void* d_ws, size_t ws_size,
                              hipStream_t stream) {
    const float* x      = (const float*)d_in[0];
    const int*   ei     = (const int*)d_in[1];
    const int*   batch  = (const int*)d_in[2];
    const float* W1     = (const float*)d_in[3];
    const float* a_src1 = (const float*)d_in[4];
    const float* a_dst1 = (const float*)d_in[5];
    const float* b1     = (const float*)d_in[6];
    const float* W2     = (const float*)d_in[7];
    const float* a_src2 = (const float*)d_in[8];
    const float* a_dst2 = (const float*)d_in[9];
    const float* b2     = (const float*)d_in[10];
    const float* W3     = (const float*)d_in[11];
    const float* a_src3 = (const float*)d_in[12];
    const float* a_dst3 = (const float*)d_in[13];
    const float* b3     = (const float*)d_in[14];
    const float* Wc     = (const float*)d_in[15];
    const float* bc     = (const float*)d_in[16];

    const int N    = in_sizes[2];
    const int E    = in_sizes[1] / 2;
    const int F_IN = in_sizes[0] / N;   // 128
    const int HC   = in_sizes[6];       // 256
    const int C    = in_sizes[14];      // 64
    const int NC   = in_sizes[16];      // 200
    const int Etot = E + N;
    const int NB   = (N + 1023) / 1024;
    const int NPB  = (N + POOL_CHUNK - 1) / POOL_CHUNK;

    char* w = (char*)d_ws;
    size_t off = 0;
    auto alloc = [&](size_t bytes) -> void* {
        void* p = w + off;
        off = align_up(off + bytes, 256);
        return p;
    };
    int*   deg    = (int*)alloc((size_t)N * 4);
    // sums + counts + done in one prep-zeroed region
    float* sums   = (float*)alloc((size_t)(64 * 64 + 64 + 1) * 4);
    float* counts = sums + 64 * 64;
    int*   done   = (int*)(counts + 64);
    int*   rowptr = (int*)alloc((size_t)(N + 1) * 4);
    int*   epos   = (int*)alloc((size_t)E * 4);
    int*   srcs   = (int*)alloc((size_t)Etot * 4);
    int*   aggst  = (int*)alloc((size_t)(NB + 1) * 4);
    float* as_buf = (float*)alloc((size_t)N * 4 * 4);
    float* ad_buf = (float*)alloc((size_t)N * 4 * 4);
    unsigned short* Wt1 = (unsigned short*)alloc((size_t)HC * F_IN * 2);
    unsigned short* Wt2 = (unsigned short*)alloc((size_t)HC * HC * 2);
    unsigned short* Wt3 = (unsigned short*)alloc((size_t)C * HC * 2);
    unsigned short* wasd1 = (unsigned short*)alloc((size_t)16 * F_IN * 2);
    unsigned short* wasd2 = (unsigned short*)alloc((size_t)16 * HC * 2);
    unsigned short* wasd3 = (unsigned short*)alloc((size_t)16 * HC * 2);
    unsigned char*  hA  = (unsigned char*)alloc((size_t)N * HC);      // fp8 h-table
    unsigned short* hB  = (unsigned short*)alloc((size_t)N * HC * 2); // bf16 agg out
    unsigned short* hC  = (unsigned short*)alloc((size_t)N * C * 2);
    float* bufF   = (float*)alloc((size_t)N * C * 4);

    const int TPB = 256;

    // ---- weight casts + w_asd + zeroing (deg/sums/done) + scan arming ----
    int n1 = HC * F_IN, n2 = HC * HC, n3 = C * HC;
    int ntot = n1 + n2 + n3 + 16 * F_IN + 16 * HC + 16 * HC;
    int zn = 64 * 64 + 64 + 1;
    int gPrep = (max(ntot, N) + TPB - 1) / TPB;
    prep_weights<<<gPrep, TPB, 0, stream>>>(
        W1, Wt1, W2, Wt2, W3, Wt3,
        a_src1, a_dst1, a_src2, a_dst2, a_src3, a_dst3,
        wasd1, wasd2, wasd3, deg, sums, aggst, N, zn, NB, n1, n2, n3, F_IN, HC, C);

    // ---- CSR build: count -> fused lookback scan -> scatter ----
    count_edges<<<(E + TPB - 1) / TPB, TPB, 0, stream>>>(ei, deg, epos, E);
    scan_fused<<<NB, 256, 0, stream>>>(deg, rowptr, aggst, N, NB);
    scatter_edges<<<(Etot + TPB - 1) / TPB, TPB, 0, stream>>>(ei, rowptr, deg, epos, srcs, E, N);

    dim3 gWide(1, (N + 63) / 64);        // BM=64 x BN=256
    dim3 gNarrow(1, (N + 255) / 256);    // BM=256 x BN=64
    int aggBlocks12 = (N + 7) / 8;               // NPW=2: 8 nodes/block
    int aggBlocks3  = (((N + 3) / 4) + 3) / 4;   // NPW=4

    // ---- Layer 1 (A = f32 x, converted in staging; C -> fp8 hA) ----
    gemm_bf16<true, 4, true><<<gWide, 256, 0, stream>>>(x, Wt1, wasd1, hA, as_buf, ad_buf, N, HC, F_IN, 4);
    gat_aggregate<4, 2, 8, false, true><<<aggBlocks12, 256, 0, stream>>>(hA, as_buf, ad_buf, rowptr, srcs, b1, hB, N);

    // ---- Layer 2 (A = bf16 hB; C -> fp8 hA) ----
    gemm_bf16<false, 4, true><<<gWide, 256, 0, stream>>>(hB, Wt2, wasd2, hA, as_buf, ad_buf, N, HC, HC, 4);
    gat_aggregate<4, 2, 8, false, true><<<aggBlocks12, 256, 0, stream>>>(hA, as_buf, ad_buf, rowptr, srcs, b2, hB, N);

    // ---- Layer 3 (H=1; bf16 throughout) ----
    gemm_bf16<false, 1, false><<<gNarrow, 256, 0, stream>>>(hB, Wt3, wasd3, hC, as_buf, ad_buf, N, C, HC, 1);
    gat_aggregate<1, 4, 4, true, false><<<aggBlocks3, 256, 0, stream>>>(hC, as_buf, ad_buf, rowptr, srcs, b3, bufF, N);

    // ---- Pool + classify (one dispatch, last-block classifies) ----
    pool_classify<<<NPB, 256, 0, stream>>>(bufF, batch, sums, counts, Wc, bc,
                                           (float*)d_out, done, N, NC, NPB);
}

// Round 14
// 387.491 us; speedup vs baseline: 1.0563x; 1.0563x over previous
//
#include <hip/hip_runtime.h>
#include <hip/hip_fp8.h>

// ---------------------------------------------------------------------------
// GAT 3-layer classifier. CSR build -> per layer: mfma-gemm(+attn coefs) ->
// aggregate -> pool/cls.
// R17: as/ad folded into GEMM via precomputed w_asd; dbuf one-barrier GEMM.
// R22: fp8 e4m3 h-table layers 1-2. R24: pk-FMA agg 48->43.4us.
// R25 (340.4us): pk-FMA + memset folded into prep. 13 dispatches.
// R26: (a) scan_partial+scan_blocks fused via parallel aggregate lookback,
//      rowptr ABSOLUTE (bs[] gathers deleted) -- WORKED (~-28us by
//      subtraction); (b) pool+classify last-block merge -- BACKFIRED:
//      single-block classify re-reading Wc from global 64x = 107us tail
//      (old classify used 64 parallel blocks; estimate was wrong).
// R27 (this): keep (a); fix (b): last block stages Wc (51KB) + all 64
//      pooled vectors (16KB) into LDS once, then 256 threads compute
//      strided (graph,class) outputs -- ~3200 LDS-FMA/thread ~= 4us.
// ---------------------------------------------------------------------------

typedef __attribute__((ext_vector_type(8))) __bf16 bf16x8;
typedef __attribute__((ext_vector_type(4))) float f32x4;
typedef __attribute__((ext_vector_type(2))) float f32x2;
typedef __attribute__((ext_vector_type(8))) unsigned short u16x8;

#define LOG2E 1.44269504f
#define NC_MAX 200

static __device__ __forceinline__ unsigned short f2bf(float f) {
    unsigned u = __float_as_uint(f);
    unsigned r = (u + 0x7fffu + ((u >> 16) & 1u)) >> 16;
    return (unsigned short)r;
}
static __device__ __forceinline__ float bf2f(unsigned short s) {
    return __uint_as_float(((unsigned)s) << 16);
}

// ---- fp8 e4m3 (OCP) encode/decode, HW cvt when available ----
#if __has_builtin(__builtin_amdgcn_cvt_pk_fp8_f32)
static __device__ __forceinline__ unsigned char f2fp8(float v) {
    return (unsigned char)(__builtin_amdgcn_cvt_pk_fp8_f32(v, v, 0, false) & 0xff);
}
#else
static __device__ __forceinline__ unsigned char f2fp8(float v) {
    return (unsigned char)__hip_cvt_float_to_fp8(v, __HIP_SATFINITE, __HIP_E4M3);
}
#endif

#if __has_builtin(__builtin_amdgcn_cvt_pk_f32_fp8)
template <bool HI>
static __device__ __forceinline__ f32x2 fp8pair(unsigned int w) {
    return __builtin_amdgcn_cvt_pk_f32_fp8(w, HI);   // HI literal per instantiation
}
#else
static __device__ __forceinline__ float fp8one(unsigned char x) {
    __half_raw hr = __hip_cvt_fp8_to_halfraw((__hip_fp8_storage_t)x, __HIP_E4M3);
    return __half2float(*(const __half*)&hr);
}
template <bool HI>
static __device__ __forceinline__ f32x2 fp8pair(unsigned int w) {
    unsigned int s = HI ? (w >> 16) : w;
    f32x2 r;
    r[0] = fp8one((unsigned char)(s & 0xff));
    r[1] = fp8one((unsigned char)((s >> 8) & 0xff));
    return r;
}
#endif

static __device__ __forceinline__ void g2lds16(const unsigned short* g,
                                               unsigned short* l) {
    __builtin_amdgcn_global_load_lds(
        (const __attribute__((address_space(1))) unsigned int*)g,
        (__attribute__((address_space(3))) unsigned int*)l, 16, 0, 0);
}

// ============================ CSR build ====================================
__global__ void count_edges(const int* __restrict__ ei, int* __restrict__ deg,
                            int* __restrict__ epos, int E) {
    int i = blockIdx.x * blockDim.x + threadIdx.x;
    if (i >= E) return;
    int dst = ei[E + i];
    epos[i] = atomicAdd(&deg[dst], 1);
}

// Merged scan: per-1024-chunk exclusive scan of (deg[i]+1) with parallel
// aggregate-lookback across chunks.  aggst[b] (init -1 by prep) holds chunk
// b's total once published.  rowptr is written ABSOLUTE; last chunk writes
// rowptr[N] = grand total.  (R26, validated.)
__global__ __launch_bounds__(256) void scan_fused(const int* __restrict__ deg,
                                                  int* __restrict__ rowptr,
                                                  int* __restrict__ aggst,
                                                  int N, int NB) {
    int b = blockIdx.x;
    int t = threadIdx.x;
    int lane = t & 63, wv = t >> 6;
    int base = b * 1024 + t * 4;
    int v[4];
#pragma unroll
    for (int j = 0; j < 4; ++j) v[j] = (base + j < N) ? deg[base + j] + 1 : 0;
    int local = v[0] + v[1] + v[2] + v[3];
    int x = local;
#pragma unroll
    for (int off = 1; off < 64; off <<= 1) {
        int y = __shfl_up(x, off);
        if (lane >= off) x += y;
    }
    __shared__ int wsum[4];
    __shared__ int prevSh;
    if (lane == 63) wsum[wv] = x;
    __syncthreads();
    int tot = wsum[0] + wsum[1] + wsum[2] + wsum[3];
    if (t == 0)   // publish this chunk's aggregate immediately (release)
        __hip_atomic_store(&aggst[b], tot, __ATOMIC_RELEASE, __HIP_MEMORY_SCOPE_AGENT);
    int woff = 0;
    for (int i = 0; i < wv; ++i) woff += wsum[i];
    // wave 0: parallel lookback — lane l polls predecessor l's aggregate.
    if (wv == 0) {
        int pref = 0;
        for (int b0 = 0; b0 < b; b0 += 64) {
            int idx = b0 + lane;
            int va = 0;
            if (idx < b) {
                do {
                    va = __hip_atomic_load(&aggst[idx], __ATOMIC_ACQUIRE,
                                           __HIP_MEMORY_SCOPE_AGENT);
                } while (va < 0);
            }
#pragma unroll
            for (int off = 32; off >= 1; off >>= 1) va += __shfl_xor(va, off);
            pref += va;    // butterfly leaves the sum in all lanes
        }
        if (lane == 0) {
            prevSh = pref;
            if (b == NB - 1) rowptr[N] = pref + tot;
        }
    }
    __syncthreads();
    int run = prevSh + woff + x - local;
#pragma unroll
    for (int j = 0; j < 4; ++j) {
        if (base + j < N) rowptr[base + j] = run;
        run += v[j];
    }
}

// atomic-free scatter (rowptr absolute).
__global__ void scatter_edges(const int* __restrict__ ei, const int* __restrict__ rowptr,
                              const int* __restrict__ deg, const int* __restrict__ epos,
                              int* __restrict__ srcs, int E, int N) {
    int i = blockIdx.x * blockDim.x + threadIdx.x;
    int tot = E + N;
    if (i >= tot) return;
    if (i < E) {
        int dst = ei[E + i];
        srcs[rowptr[dst] + epos[i]] = ei[i];
    } else {
        int d = i - E;
        srcs[rowptr[d] + deg[d]] = d;
    }
}

// ================= fused weight casts + attn weights + zeroing =============
// Also zeroes deg[0..N), sums/counts/done (zsums[0..zn)), and arms the scan
// lookback slots aggst[0..NB) = -1.  Runs before count_edges each launch.
// w_asd[p][k] = sum_c W[k, h*C+c] * a[h][c]  (p<H: a_src, H<=p<2H: a_dst,
// p>=2H: 0).  16 rows x K bf16 per layer, k-contiguous (Bt layout).
__global__ void prep_weights(const float* __restrict__ W1, unsigned short* __restrict__ Wt1,
                             const float* __restrict__ W2, unsigned short* __restrict__ Wt2,
                             const float* __restrict__ W3, unsigned short* __restrict__ Wt3,
                             const float* __restrict__ as1, const float* __restrict__ ad1,
                             const float* __restrict__ as2, const float* __restrict__ ad2,
                             const float* __restrict__ as3, const float* __restrict__ ad3,
                             unsigned short* __restrict__ wasd1,
                             unsigned short* __restrict__ wasd2,
                             unsigned short* __restrict__ wasd3,
                             int* __restrict__ deg, float* __restrict__ zsums,
                             int* __restrict__ aggst,
                             int N, int zn, int NB,
                             int n1, int n2, int n3, int F_IN, int HC, int C) {
    int i = blockIdx.x * blockDim.x + threadIdx.x;
    if (i < N) deg[i] = 0;
    if (i < zn) zsums[i] = 0.f;
    if (i < NB) aggst[i] = -1;
    if (i < n1) {  // Wt1: [HC][F_IN]
        int n = i / F_IN, k = i - n * F_IN;
        Wt1[i] = f2bf(W1[(size_t)k * HC + n]);
        return;
    }
    i -= n1;
    if (i < n2) {  // Wt2: [HC][HC]
        int n = i / HC, k = i - n * HC;
        Wt2[i] = f2bf(W2[(size_t)k * HC + n]);
        return;
    }
    i -= n2;
    if (i < n3) {  // Wt3: [C][HC]
        int n = i / HC, k = i - n * HC;
        Wt3[i] = f2bf(W3[(size_t)k * C + n]);
        return;
    }
    i -= n3;
    if (i < 16 * 128) {               // wasd1: K=128, H=4, C=64
        int p = i >> 7, k = i & 127;
        float v = 0.f;
        if (p < 8) {
            const float* a = (p < 4) ? as1 : ad1;
            int hh = p & 3;
            for (int c = 0; c < 64; ++c)
                v += W1[(size_t)k * 256 + hh * 64 + c] * a[hh * 64 + c];
        }
        wasd1[i] = f2bf(v);
        return;
    }
    i -= 16 * 128;
    if (i < 16 * 256) {               // wasd2: K=256, H=4, C=64
        int p = i >> 8, k = i & 255;
        float v = 0.f;
        if (p < 8) {
            const float* a = (p < 4) ? as2 : ad2;
            int hh = p & 3;
            for (int c = 0; c < 64; ++c)
                v += W2[(size_t)k * 256 + hh * 64 + c] * a[hh * 64 + c];
        }
        wasd2[i] = f2bf(v);
        return;
    }
    i -= 16 * 256;
    if (i < 16 * 256) {               // wasd3: K=256, H=1, C=64
        int p = i >> 8, k = i & 255;
        float v = 0.f;
        if (p < 2) {
            const float* a = p ? ad3 : as3;
            for (int c = 0; c < 64; ++c)
                v += W3[(size_t)k * 64 + c] * a[c];
        }
        wasd3[i] = f2bf(v);
    }
}

// ============================ MFMA GEMM + fused attn coefs =================
// C[M,BN] = A[M,K] @ Bt[BN,K](bf16)^T, BN == N exactly (grid.x=1).
// WAVES_N=4: BM=64, BN=256 (wave==head).  WAVES_N=1: BM=256, BN=64.
// Double-buffered LDS, one barrier per K-step (R17).  as/ad via one extra
// MFMA per A-frag against the precomputed w_asd fragment; stored from the
// accumulator with LOG2E fold.  C8: C stored as fp8 e4m3 (byte/lane).
#define BK 32

template <bool AF32, int WAVES_N, bool C8>
__global__ __launch_bounds__(256) void gemm_bf16(const void* __restrict__ Av,
                                                 const unsigned short* __restrict__ Bt,
                                                 const unsigned short* __restrict__ Wasd,
                                                 void* __restrict__ Cv,
                                                 float* __restrict__ as_o,
                                                 float* __restrict__ ad_o,
                                                 int M, int N, int K, int H) {
    constexpr int BMt = (4 / WAVES_N) * 64;
    constexpr int BNt = WAVES_N * 64;
    constexpr int ASLOTS = BMt * 4;               // 16B slots for the A tile
    constexpr int ROUNDS = (BMt + BNt) / 64;      // g2lds rounds (non-AF32)
    constexpr bool ASD_ALL = (WAVES_N == 1);
    __shared__ unsigned short As[2][BMt * BK];
    __shared__ unsigned short Bs[2][BNt * BK];
    __shared__ unsigned short Ws[2][16 * BK];
    int t = threadIdx.x;
    int bm = blockIdx.y * BMt;
    int wave = t >> 6, lane = t & 63;
    int wm = (wave / WAVES_N) * 64, wn = (wave % WAVES_N) * 64;
    int quad = lane >> 4, mr = lane & 15;

    f32x4 zero = {0.f, 0.f, 0.f, 0.f};
    f32x4 acc[4][4];
#pragma unroll
    for (int i = 0; i < 4; ++i)
#pragma unroll
        for (int j = 0; j < 4; ++j) acc[i][j] = zero;
    f32x4 acc4[4];
#pragma unroll
    for (int i = 0; i < 4; ++i) acc4[i] = zero;

    int sw = quad ^ ((mr >> 1) & 3);
    int aoff[4], boff[4];
#pragma unroll
    for (int i = 0; i < 4; ++i) {
        aoff[i] = (wm + i * 16 + mr) * BK + sw * 8;
        boff[i] = (wn + i * 16 + mr) * BK + sw * 8;
    }

    auto stage_ab = [&](int bsel, int kk) {
        const unsigned short* Ab = (const unsigned short*)Av;
#pragma unroll
        for (int r = 0; r < ROUNDS; ++r) {
            int slotw = r * 256 + wave * 64;      // wave-uniform slot base
            int slot = slotw + lane;
            if (slotw < ASLOTS) {
                int row = slot >> 2;
                int sg = (slot & 3) ^ ((row >> 1) & 3);
                int gra = bm + row;
                if (gra < M)
                    g2lds16(&Ab[(size_t)gra * K + kk + sg * 8], &As[bsel][slotw * 8]);
            } else {
                int bslot = slot - ASLOTS;
                int row = bslot >> 2;
                int sg = (bslot & 3) ^ ((row >> 1) & 3);
                g2lds16(&Bt[(size_t)row * K + kk + sg * 8], &Bs[bsel][(slotw - ASLOTS) * 8]);
            }
        }
        if (wave == 0)
            g2lds16(&Wasd[(size_t)(lane >> 2) * K + kk + (lane & 3) * 8], &Ws[bsel][0]);
    };
    auto stage_b_af32 = [&](int bsel, int kk) {
#pragma unroll
        for (int r = 0; r < BNt / 64; ++r) {
            int slotw = r * 256 + wave * 64;
            int bslot = slotw + lane;
            int row = bslot >> 2;
            int sg = (bslot & 3) ^ ((row >> 1) & 3);
            g2lds16(&Bt[(size_t)row * K + kk + sg * 8], &Bs[bsel][slotw * 8]);
        }
        if (wave == 0)
            g2lds16(&Wasd[(size_t)(lane >> 2) * K + kk + (lane & 3) * 8], &Ws[bsel][0]);
    };
    auto loadA_f32 = [&](int kk, float4& lo, float4& hi) {
        int slot = t, row = slot >> 2;
        int sg = (slot & 3) ^ ((row >> 1) & 3);
        int gra = bm + row;
        lo = make_float4(0.f, 0.f, 0.f, 0.f); hi = lo;
        if (gra < M) {
            const float* Af = (const float*)Av;
            lo = *(const float4*)&Af[(size_t)gra * K + kk + sg * 8];
            hi = *(const float4*)&Af[(size_t)gra * K + kk + sg * 8 + 4];
        }
    };
    auto writeA = [&](int bsel, float4 lo, float4 hi) {
        int slot = t;
        *(ushort4*)&As[bsel][slot * 8]     = make_ushort4(f2bf(lo.x), f2bf(lo.y), f2bf(lo.z), f2bf(lo.w));
        *(ushort4*)&As[bsel][slot * 8 + 4] = make_ushort4(f2bf(hi.x), f2bf(hi.y), f2bf(hi.z), f2bf(hi.w));
    };

    const int nt = K / BK;
    int cur = 0;

    if (AF32) {
        float4 l0, h0;
        loadA_f32(0, l0, h0);
        writeA(0, l0, h0);
        stage_b_af32(0, 0);
    } else {
        stage_ab(0, 0);
    }
    __syncthreads();

    for (int ts = 0; ts < nt; ++ts) {
        int nxt = cur ^ 1;
        bool more = (ts + 1 < nt);
        float4 plo, phi;
        if (more) {
            if (AF32) {
                loadA_f32((ts + 1) * BK, plo, phi);      // issue early
                stage_b_af32(nxt, (ts + 1) * BK);
            } else {
                stage_ab(nxt, (ts + 1) * BK);
            }
        }
        bf16x8 af[4], bfr[4];
#pragma unroll
        for (int i = 0; i < 4; ++i) {
            af[i]  = *(bf16x8*)&As[cur][aoff[i]];
            bfr[i] = *(bf16x8*)&Bs[cur][boff[i]];
        }
#pragma unroll
        for (int i = 0; i < 4; ++i)
#pragma unroll
            for (int j = 0; j < 4; ++j)
                acc[i][j] = __builtin_amdgcn_mfma_f32_16x16x32_bf16(af[i], bfr[j], acc[i][j], 0, 0, 0);
        if (ASD_ALL || wave == 0) {
            bf16x8 wsf = *(bf16x8*)&Ws[cur][mr * BK + quad * 8];
#pragma unroll
            for (int i = 0; i < 4; ++i)
                acc4[i] = __builtin_amdgcn_mfma_f32_16x16x32_bf16(af[i], wsf, acc4[i], 0, 0, 0);
        }
        if (more && AF32) writeA(nxt, plo, phi);         // write late
        __syncthreads();
        cur = nxt;
    }

    // as/ad store: D col=mr is coefficient index p (p<H: as, else ad)
    if ((ASD_ALL || wave == 0) && mr < 2 * H) {
#pragma unroll
        for (int i = 0; i < 4; ++i)
#pragma unroll
            for (int r = 0; r < 4; ++r) {
                int grow = bm + wm + i * 16 + quad * 4 + r;
                if (grow >= M) continue;
                float v = acc4[i][r] * LOG2E;
                if (mr < H) as_o[(size_t)grow * H + mr] = v;
                else        ad_o[(size_t)grow * H + (mr - H)] = v;
            }
    }

    // C store: C/D layout col=lane&15, row=quad*4+reg
#pragma unroll
    for (int i = 0; i < 4; ++i) {
#pragma unroll
        for (int r = 0; r < 4; ++r) {
            int grow = bm + wm + i * 16 + quad * 4 + r;
            if (grow >= M) continue;
#pragma unroll
            for (int j = 0; j < 4; ++j) {
                int gcol = wn + j * 16 + mr;
                if constexpr (C8) {
                    ((unsigned char*)Cv)[(size_t)grow * N + gcol] = f2fp8(acc[i][j][r]);
                } else {
                    ((unsigned short*)Cv)[(size_t)grow * N + gcol] = f2bf(acc[i][j][r]);
                }
            }
        }
    }
}

// ============================ aggregation ==================================
// Single-pass unnormalized softmax: out = sum(exp(e)*h) / (sum(exp(e))+eps).
// as/ad pre-scaled by log2(e) -> exp2; leaky = fmax(e, 0.2e).
// IN8 VPL=8: NPW=2, uint2 8B/lane; f32x2 accumulate -> v_pk_fma_f32.
// rowptr is ABSOLUTE — no chunk-offset gathers.
template <int H, int NPW, int VPL, bool OUTF32, bool IN8>
__global__ __launch_bounds__(256) void gat_aggregate(const void* __restrict__ hbuf_v,
                                                     const float* __restrict__ as_i,
                                                     const float* __restrict__ ad_i,
                                                     const int* __restrict__ rowptr,
                                                     const int* __restrict__ srcs,
                                                     const float* __restrict__ bias,
                                                     void* __restrict__ out_v, int N) {
    constexpr int LPN = 64 / NPW;        // lanes per node
    constexpr int HC = LPN * VPL;        // channels per node
    int wid = (blockIdx.x * blockDim.x + threadIdx.x) >> 6;
    int lane = threadIdx.x & 63;
    int sub = lane / LPN;                // which node within the wave
    int li  = lane % LPN;                // lane within node
    int node = wid * NPW + sub;
    if (node >= N) return;
    int row = rowptr[node];
    int end = rowptr[node + 1];
    int len = end - row;
    const int hd_lane = (li * VPL) >> 6; // head = channel/64

    float advh = ad_i[(size_t)node * H + hd_lane];

    float acc[VPL] __attribute__((aligned(16)));
#pragma unroll
    for (int j = 0; j < VPL; ++j) acc[j] = 0.f;
    float l = 0.f;

    const int U = 8;
    for (int base = 0; base < len; base += U) {
        int s[U];
        float cf[U];
#pragma unroll
        for (int u = 0; u < U; ++u) {
            int idx = base + u;
            int ii = row + ((idx < len) ? idx : (len - 1));
            s[u] = srcs[ii];
        }
#pragma unroll
        for (int u = 0; u < U; ++u) cf[u] = as_i[(size_t)s[u] * H + hd_lane];
        if constexpr (IN8 && VPL == 8) {
            // fp8 path: 8 channels = 8 bytes per edge-lane (uint2);
            // f32x2 accumulate -> v_pk_fma_f32
            const unsigned char* hb = (const unsigned char*)hbuf_v;
            uint2 r[U];
#pragma unroll
            for (int u = 0; u < U; ++u)
                r[u] = *(const uint2*)&hb[(size_t)s[u] * HC + li * VPL];
            f32x2* acc2 = (f32x2*)acc;
#pragma unroll
            for (int u = 0; u < U; ++u) {
                float e = cf[u] + advh;
                e = fmaxf(e, 0.2f * e);
                float wgt = (base + u < len) ? exp2f(e) : 0.f;
                l += wgt;
                f32x2 w2 = {wgt, wgt};
                acc2[0] += w2 * fp8pair<false>(r[u].x);
                acc2[1] += w2 * fp8pair<true >(r[u].x);
                acc2[2] += w2 * fp8pair<false>(r[u].y);
                acc2[3] += w2 * fp8pair<true >(r[u].y);
            }
        } else if constexpr (VPL == 8) {
            const unsigned short* hb = (const unsigned short*)hbuf_v;
            u16x8 r[U];
#pragma unroll
            for (int u = 0; u < U; ++u)
                r[u] = *(const u16x8*)&hb[(size_t)s[u] * HC + li * 8];
#pragma unroll
            for (int u = 0; u < U; ++u) {
                float e = cf[u] + advh;
                e = fmaxf(e, 0.2f * e);
                float wgt = (base + u < len) ? exp2f(e) : 0.f;
                l += wgt;
#pragma unroll
                for (int j = 0; j < 8; ++j) acc[j] += wgt * bf2f(r[u][j]);
            }
        } else {
            const unsigned short* hb = (const unsigned short*)hbuf_v;
            ushort4 r[U];
#pragma unroll
            for (int u = 0; u < U; ++u)
                r[u] = *(const ushort4*)&hb[(size_t)s[u] * HC + li * 4];
#pragma unroll
            for (int u = 0; u < U; ++u) {
                float e = cf[u] + advh;
                e = fmaxf(e, 0.2f * e);
                float wgt = (base + u < len) ? exp2f(e) : 0.f;
                l += wgt;
                acc[0] += wgt * bf2f(r[u].x);
                acc[1] += wgt * bf2f(r[u].y);
                acc[2] += wgt * bf2f(r[u].z);
                acc[3] += wgt * bf2f(r[u].w);
            }
        }
    }

    float inv_l = 1.f / (l + 1e-16f);
    float vals[VPL];
#pragma unroll
    for (int j = 0; j < VPL; ++j) {
        float v = acc[j] * inv_l + bias[li * VPL + j];
        vals[j] = (v > 0.f) ? v : (__expf(v) - 1.f);
    }
    if constexpr (OUTF32) {
        float* out = (float*)out_v;
        if constexpr (VPL == 4) {
            float4 o = make_float4(vals[0], vals[1], vals[2], vals[3]);
            *(float4*)&out[(size_t)node * HC + li * 4] = o;
        } else {
#pragma unroll
            for (int j = 0; j < VPL; ++j)
                out[(size_t)node * HC + li * VPL + j] = vals[j];
        }
    } else {
        unsigned short* out = (unsigned short*)out_v;
        if constexpr (VPL == 8) {
            u16x8 o;
#pragma unroll
            for (int j = 0; j < 8; ++j) o[j] = f2bf(vals[j]);
            *(u16x8*)&out[(size_t)node * HC + li * 8] = o;
        } else {
            ushort4 o;
            o.x = f2bf(vals[0]); o.y = f2bf(vals[1]);
            o.z = f2bf(vals[2]); o.w = f2bf(vals[3]);
            *(ushort4*)&out[(size_t)node * HC + li * 4] = o;
        }
    }
}

// ====================== pool + classify (last-block, LDS) ==================
#define POOL_CHUNK 128
__global__ __launch_bounds__(256) void pool_classify(const float* __restrict__ hf,
                                                     const int* __restrict__ batch,
                                                     float* __restrict__ sums,
                                                     float* __restrict__ counts,
                                                     const float* __restrict__ Wc,
                                                     const float* __restrict__ bc,
                                                     float* __restrict__ out,
                                                     int* __restrict__ done,
                                                     int N, int NC, int NPB) {
    // LDS: Wc (64 x NC_MAX) + pooled vectors p (64 graphs x 64 ch)
    __shared__ float WcS[64 * NC_MAX];
    __shared__ float pS[64 * 64];
    int t = threadIdx.x;
    int c = t & 63, sub = t >> 6;
    int start = blockIdx.x * POOL_CHUNK;
    int end = min(start + POOL_CHUNK, N);
    float acc = 0.f, cnt = 0.f;
    int cur = -1;
    for (int n = start + sub; n < end; n += 4) {
        int g = batch[n];
        if (g != cur) {
            if (cur >= 0) {
                atomicAdd(&sums[cur * 64 + c], acc);
                if (c == 0) atomicAdd(&counts[cur], cnt);
            }
            cur = g; acc = 0.f; cnt = 0.f;
        }
        acc += hf[(size_t)n * 64 + c];
        cnt += 1.f;
    }
    if (cur >= 0) {
        atomicAdd(&sums[cur * 64 + c], acc);
        if (c == 0) atomicAdd(&counts[cur], cnt);
    }

    // last-block-done: the final block to finish pooling runs classification.
    __threadfence();
    __syncthreads();
    __shared__ int ticket;
    if (t == 0) ticket = atomicAdd(done, 1);
    __syncthreads();
    if (ticket != NPB - 1) return;
    __threadfence();   // acquire: all other blocks' atomics now visible

    // stage Wc + pooled vectors into LDS (coalesced), then strided outputs
    int nwc = 64 * NC;
    for (int i = t; i < nwc; i += 256) WcS[i] = Wc[i];
    for (int i = t; i < 64 * 64; i += 256) {
        int g = i >> 6, cc = i & 63;
        pS[i] = sums[g * 64 + cc] / fmaxf(counts[g], 1.0f);
    }
    __syncthreads();
    for (int o = t; o < 64 * NC; o += 256) {
        int g = o / NC, k = o - g * NC;
        float a = bc[k];
        const float* pg = &pS[g * 64];
#pragma unroll 8
        for (int cc = 0; cc < 64; ++cc) a += pg[cc] * WcS[cc * NC + k];
        out[o] = a;
    }
}

static inline size_t align_up(size_t x, size_t a) { return (x + a - 1) / a * a; }

extern "C" void kernel_launch(void* const* d_in, const int* in_sizes, int n_in,
                              void* d_out, int out_size, void* d_ws, size_t ws_size,
                              hipStream_t stream) {
    const float* x      = (const float*)d_in[0];
    const int*   ei     = (const int*)d_in[1];
    const int*   batch  = (const int*)d_in[2];
    const float* W1     = (const float*)d_in[3];
    const float* a_src1 = (const float*)d_in[4];
    const float* a_dst1 = (const float*)d_in[5];
    const float* b1     = (const float*)d_in[6];
    const float* W2     = (const float*)d_in[7];
    const float* a_src2 = (const float*)d_in[8];
    const float* a_dst2 = (const float*)d_in[9];
    const float* b2     = (const float*)d_in[10];
    const float* W3     = (const float*)d_in[11];
    const float* a_src3 = (const float*)d_in[12];
    const float* a_dst3 = (const float*)d_in[13];
    const float* b3     = (const float*)d_in[14];
    const float* Wc     = (const float*)d_in[15];
    const float* bc     = (const float*)d_in[16];

    const int N    = in_sizes[2];
    const int E    = in_sizes[1] / 2;
    const int F_IN = in_sizes[0] / N;   // 128
    const int HC   = in_sizes[6];       // 256
    const int C    = in_sizes[14];      // 64
    const int NC   = in_sizes[16];      // 200 (<= NC_MAX)
    const int Etot = E + N;
    const int NB   = (N + 1023) / 1024;
    const int NPB  = (N + POOL_CHUNK - 1) / POOL_CHUNK;

    char* w = (char*)d_ws;
    size_t off = 0;
    auto alloc = [&](size_t bytes) -> void* {
        void* p = w + off;
        off = align_up(off + bytes, 256);
        return p;
    };
    int*   deg    = (int*)alloc((size_t)N * 4);
    // sums + counts + done in one prep-zeroed region
    float* sums   = (float*)alloc((size_t)(64 * 64 + 64 + 1) * 4);
    float* counts = sums + 64 * 64;
    int*   done   = (int*)(counts + 64);
    int*   rowptr = (int*)alloc((size_t)(N + 1) * 4);
    int*   epos   = (int*)alloc((size_t)E * 4);
    int*   srcs   = (int*)alloc((size_t)Etot * 4);
    int*   aggst  = (int*)alloc((size_t)(NB + 1) * 4);
    float* as_buf = (float*)alloc((size_t)N * 4 * 4);
    float* ad_buf = (float*)alloc((size_t)N * 4 * 4);
    unsigned short* Wt1 = (unsigned short*)alloc((size_t)HC * F_IN * 2);
    unsigned short* Wt2 = (unsigned short*)alloc((size_t)HC * HC * 2);
    unsigned short* Wt3 = (unsigned short*)alloc((size_t)C * HC * 2);
    unsigned short* wasd1 = (unsigned short*)alloc((size_t)16 * F_IN * 2);
    unsigned short* wasd2 = (unsigned short*)alloc((size_t)16 * HC * 2);
    unsigned short* wasd3 = (unsigned short*)alloc((size_t)16 * HC * 2);
    unsigned char*  hA  = (unsigned char*)alloc((size_t)N * HC);      // fp8 h-table
    unsigned short* hB  = (unsigned short*)alloc((size_t)N * HC * 2); // bf16 agg out
    unsigned short* hC  = (unsigned short*)alloc((size_t)N * C * 2);
    float* bufF   = (float*)alloc((size_t)N * C * 4);

    const int TPB = 256;

    // ---- weight casts + w_asd + zeroing (deg/sums/done) + scan arming ----
    int n1 = HC * F_IN, n2 = HC * HC, n3 = C * HC;
    int ntot = n1 + n2 + n3 + 16 * F_IN + 16 * HC + 16 * HC;
    int zn = 64 * 64 + 64 + 1;
    int gPrep = (max(ntot, N) + TPB - 1) / TPB;
    prep_weights<<<gPrep, TPB, 0, stream>>>(
        W1, Wt1, W2, Wt2, W3, Wt3,
        a_src1, a_dst1, a_src2, a_dst2, a_src3, a_dst3,
        wasd1, wasd2, wasd3, deg, sums, aggst, N, zn, NB, n1, n2, n3, F_IN, HC, C);

    // ---- CSR build: count -> fused lookback scan -> scatter ----
    count_edges<<<(E + TPB - 1) / TPB, TPB, 0, stream>>>(ei, deg, epos, E);
    scan_fused<<<NB, 256, 0, stream>>>(deg, rowptr, aggst, N, NB);
    scatter_edges<<<(Etot + TPB - 1) / TPB, TPB, 0, stream>>>(ei, rowptr, deg, epos, srcs, E, N);

    dim3 gWide(1, (N + 63) / 64);        // BM=64 x BN=256
    dim3 gNarrow(1, (N + 255) / 256);    // BM=256 x BN=64
    int aggBlocks12 = (N + 7) / 8;               // NPW=2: 8 nodes/block
    int aggBlocks3  = (((N + 3) / 4) + 3) / 4;   // NPW=4

    // ---- Layer 1 (A = f32 x, converted in staging; C -> fp8 hA) ----
    gemm_bf16<true, 4, true><<<gWide, 256, 0, stream>>>(x, Wt1, wasd1, hA, as_buf, ad_buf, N, HC, F_IN, 4);
    gat_aggregate<4, 2, 8, false, true><<<aggBlocks12, 256, 0, stream>>>(hA, as_buf, ad_buf, rowptr, srcs, b1, hB, N);

    // ---- Layer 2 (A = bf16 hB; C -> fp8 hA) ----
    gemm_bf16<false, 4, true><<<gWide, 256, 0, stream>>>(hB, Wt2, wasd2, hA, as_buf, ad_buf, N, HC, HC, 4);
    gat_aggregate<4, 2, 8, false, true><<<aggBlocks12, 256, 0, stream>>>(hA, as_buf, ad_buf, rowptr, srcs, b2, hB, N);

    // ---- Layer 3 (H=1; bf16 throughout) ----
    gemm_bf16<false, 1, false><<<gNarrow, 256, 0, stream>>>(hB, Wt3, wasd3, hC, as_buf, ad_buf, N, C, HC, 1);
    gat_aggregate<1, 4, 4, true, false><<<aggBlocks3, 256, 0, stream>>>(hC, as_buf, ad_buf, rowptr, srcs, b3, bufF, N);

    // ---- Pool + classify (one dispatch, last block classifies via LDS) ----
    pool_classify<<<NPB, 256, 0, stream>>>(bufF, batch, sums, counts, Wc, bc,
                                           (float*)d_out, done, N, NC, NPB);
}

// Round 15
// 340.035 us; speedup vs baseline: 1.2038x; 1.1396x over previous
//
#include <hip/hip_runtime.h>
#include <hip/hip_fp8.h>

// ---------------------------------------------------------------------------
// GAT 3-layer classifier. CSR build -> per layer: mfma-gemm(+attn coefs) ->
// aggregate -> pool/cls.
// R17: as/ad folded into GEMM via precomputed w_asd; dbuf one-barrier GEMM.
// R22: fp8 e4m3 h-table layers 1-2. R24: pk-FMA agg 48->43.4us.
// R25 (340.4us): pk-FMA + memset folded into prep. 13 dispatches.
// R26: scan fused via parallel aggregate lookback + ABSOLUTE rowptr (bs[]
//      gathers deleted) -- VALIDATED, ~-28us by subtraction. pool+classify
//      last-block merge backfired (single-block Wc re-reads: 107us).
// R27: LDS-staged classify tail: 85us -- the 68KB STATIC LDS is allocated
//      by ALL 391 pool blocks -> 2 blocks/CU -> pool loop latency-bound.
//      Lesson: static LDS taxes every block, not just the one using it.
// R28 (this): keep scan_fused + absolute rowptr; REVERT pool/classify to
//      the two proven high-occupancy kernels (tiny LDS, 64 parallel classify
//      blocks). 12 dispatches.
// ---------------------------------------------------------------------------

typedef __attribute__((ext_vector_type(8))) __bf16 bf16x8;
typedef __attribute__((ext_vector_type(4))) float f32x4;
typedef __attribute__((ext_vector_type(2))) float f32x2;
typedef __attribute__((ext_vector_type(8))) unsigned short u16x8;

#define LOG2E 1.44269504f

static __device__ __forceinline__ unsigned short f2bf(float f) {
    unsigned u = __float_as_uint(f);
    unsigned r = (u + 0x7fffu + ((u >> 16) & 1u)) >> 16;
    return (unsigned short)r;
}
static __device__ __forceinline__ float bf2f(unsigned short s) {
    return __uint_as_float(((unsigned)s) << 16);
}

// ---- fp8 e4m3 (OCP) encode/decode, HW cvt when available ----
#if __has_builtin(__builtin_amdgcn_cvt_pk_fp8_f32)
static __device__ __forceinline__ unsigned char f2fp8(float v) {
    return (unsigned char)(__builtin_amdgcn_cvt_pk_fp8_f32(v, v, 0, false) & 0xff);
}
#else
static __device__ __forceinline__ unsigned char f2fp8(float v) {
    return (unsigned char)__hip_cvt_float_to_fp8(v, __HIP_SATFINITE, __HIP_E4M3);
}
#endif

#if __has_builtin(__builtin_amdgcn_cvt_pk_f32_fp8)
template <bool HI>
static __device__ __forceinline__ f32x2 fp8pair(unsigned int w) {
    return __builtin_amdgcn_cvt_pk_f32_fp8(w, HI);   // HI literal per instantiation
}
#else
static __device__ __forceinline__ float fp8one(unsigned char x) {
    __half_raw hr = __hip_cvt_fp8_to_halfraw((__hip_fp8_storage_t)x, __HIP_E4M3);
    return __half2float(*(const __half*)&hr);
}
template <bool HI>
static __device__ __forceinline__ f32x2 fp8pair(unsigned int w) {
    unsigned int s = HI ? (w >> 16) : w;
    f32x2 r;
    r[0] = fp8one((unsigned char)(s & 0xff));
    r[1] = fp8one((unsigned char)((s >> 8) & 0xff));
    return r;
}
#endif

static __device__ __forceinline__ void g2lds16(const unsigned short* g,
                                               unsigned short* l) {
    __builtin_amdgcn_global_load_lds(
        (const __attribute__((address_space(1))) unsigned int*)g,
        (__attribute__((address_space(3))) unsigned int*)l, 16, 0, 0);
}

// ============================ CSR build ====================================
__global__ void count_edges(const int* __restrict__ ei, int* __restrict__ deg,
                            int* __restrict__ epos, int E) {
    int i = blockIdx.x * blockDim.x + threadIdx.x;
    if (i >= E) return;
    int dst = ei[E + i];
    epos[i] = atomicAdd(&deg[dst], 1);
}

// Merged scan: per-1024-chunk exclusive scan of (deg[i]+1) with parallel
// aggregate-lookback across chunks.  aggst[b] (init -1 by prep) holds chunk
// b's total once published.  rowptr is written ABSOLUTE; last chunk writes
// rowptr[N] = grand total.  (R26, validated.)
__global__ __launch_bounds__(256) void scan_fused(const int* __restrict__ deg,
                                                  int* __restrict__ rowptr,
                                                  int* __restrict__ aggst,
                                                  int N, int NB) {
    int b = blockIdx.x;
    int t = threadIdx.x;
    int lane = t & 63, wv = t >> 6;
    int base = b * 1024 + t * 4;
    int v[4];
#pragma unroll
    for (int j = 0; j < 4; ++j) v[j] = (base + j < N) ? deg[base + j] + 1 : 0;
    int local = v[0] + v[1] + v[2] + v[3];
    int x = local;
#pragma unroll
    for (int off = 1; off < 64; off <<= 1) {
        int y = __shfl_up(x, off);
        if (lane >= off) x += y;
    }
    __shared__ int wsum[4];
    __shared__ int prevSh;
    if (lane == 63) wsum[wv] = x;
    __syncthreads();
    int tot = wsum[0] + wsum[1] + wsum[2] + wsum[3];
    if (t == 0)   // publish this chunk's aggregate immediately (release)
        __hip_atomic_store(&aggst[b], tot, __ATOMIC_RELEASE, __HIP_MEMORY_SCOPE_AGENT);
    int woff = 0;
    for (int i = 0; i < wv; ++i) woff += wsum[i];
    // wave 0: parallel lookback — lane l polls predecessor l's aggregate.
    if (wv == 0) {
        int pref = 0;
        for (int b0 = 0; b0 < b; b0 += 64) {
            int idx = b0 + lane;
            int va = 0;
            if (idx < b) {
                do {
                    va = __hip_atomic_load(&aggst[idx], __ATOMIC_ACQUIRE,
                                           __HIP_MEMORY_SCOPE_AGENT);
                } while (va < 0);
            }
#pragma unroll
            for (int off = 32; off >= 1; off >>= 1) va += __shfl_xor(va, off);
            pref += va;    // butterfly leaves the sum in all lanes
        }
        if (lane == 0) {
            prevSh = pref;
            if (b == NB - 1) rowptr[N] = pref + tot;
        }
    }
    __syncthreads();
    int run = prevSh + woff + x - local;
#pragma unroll
    for (int j = 0; j < 4; ++j) {
        if (base + j < N) rowptr[base + j] = run;
        run += v[j];
    }
}

// atomic-free scatter (rowptr absolute).
__global__ void scatter_edges(const int* __restrict__ ei, const int* __restrict__ rowptr,
                              const int* __restrict__ deg, const int* __restrict__ epos,
                              int* __restrict__ srcs, int E, int N) {
    int i = blockIdx.x * blockDim.x + threadIdx.x;
    int tot = E + N;
    if (i >= tot) return;
    if (i < E) {
        int dst = ei[E + i];
        srcs[rowptr[dst] + epos[i]] = ei[i];
    } else {
        int d = i - E;
        srcs[rowptr[d] + deg[d]] = d;
    }
}

// ================= fused weight casts + attn weights + zeroing =============
// Also zeroes deg[0..N), sums/counts (zsums[0..zn)), and arms the scan
// lookback slots aggst[0..NB) = -1.  Runs before count_edges each launch.
// w_asd[p][k] = sum_c W[k, h*C+c] * a[h][c]  (p<H: a_src, H<=p<2H: a_dst,
// p>=2H: 0).  16 rows x K bf16 per layer, k-contiguous (Bt layout).
__global__ void prep_weights(const float* __restrict__ W1, unsigned short* __restrict__ Wt1,
                             const float* __restrict__ W2, unsigned short* __restrict__ Wt2,
                             const float* __restrict__ W3, unsigned short* __restrict__ Wt3,
                             const float* __restrict__ as1, const float* __restrict__ ad1,
                             const float* __restrict__ as2, const float* __restrict__ ad2,
                             const float* __restrict__ as3, const float* __restrict__ ad3,
                             unsigned short* __restrict__ wasd1,
                             unsigned short* __restrict__ wasd2,
                             unsigned short* __restrict__ wasd3,
                             int* __restrict__ deg, float* __restrict__ zsums,
                             int* __restrict__ aggst,
                             int N, int zn, int NB,
                             int n1, int n2, int n3, int F_IN, int HC, int C) {
    int i = blockIdx.x * blockDim.x + threadIdx.x;
    if (i < N) deg[i] = 0;
    if (i < zn) zsums[i] = 0.f;
    if (i < NB) aggst[i] = -1;
    if (i < n1) {  // Wt1: [HC][F_IN]
        int n = i / F_IN, k = i - n * F_IN;
        Wt1[i] = f2bf(W1[(size_t)k * HC + n]);
        return;
    }
    i -= n1;
    if (i < n2) {  // Wt2: [HC][HC]
        int n = i / HC, k = i - n * HC;
        Wt2[i] = f2bf(W2[(size_t)k * HC + n]);
        return;
    }
    i -= n2;
    if (i < n3) {  // Wt3: [C][HC]
        int n = i / HC, k = i - n * HC;
        Wt3[i] = f2bf(W3[(size_t)k * C + n]);
        return;
    }
    i -= n3;
    if (i < 16 * 128) {               // wasd1: K=128, H=4, C=64
        int p = i >> 7, k = i & 127;
        float v = 0.f;
        if (p < 8) {
            const float* a = (p < 4) ? as1 : ad1;
            int hh = p & 3;
            for (int c = 0; c < 64; ++c)
                v += W1[(size_t)k * 256 + hh * 64 + c] * a[hh * 64 + c];
        }
        wasd1[i] = f2bf(v);
        return;
    }
    i -= 16 * 128;
    if (i < 16 * 256) {               // wasd2: K=256, H=4, C=64
        int p = i >> 8, k = i & 255;
        float v = 0.f;
        if (p < 8) {
            const float* a = (p < 4) ? as2 : ad2;
            int hh = p & 3;
            for (int c = 0; c < 64; ++c)
                v += W2[(size_t)k * 256 + hh * 64 + c] * a[hh * 64 + c];
        }
        wasd2[i] = f2bf(v);
        return;
    }
    i -= 16 * 256;
    if (i < 16 * 256) {               // wasd3: K=256, H=1, C=64
        int p = i >> 8, k = i & 255;
        float v = 0.f;
        if (p < 2) {
            const float* a = p ? ad3 : as3;
            for (int c = 0; c < 64; ++c)
                v += W3[(size_t)k * 64 + c] * a[c];
        }
        wasd3[i] = f2bf(v);
    }
}

// ============================ MFMA GEMM + fused attn coefs =================
// C[M,BN] = A[M,K] @ Bt[BN,K](bf16)^T, BN == N exactly (grid.x=1).
// WAVES_N=4: BM=64, BN=256 (wave==head).  WAVES_N=1: BM=256, BN=64.
// Double-buffered LDS, one barrier per K-step (R17).  as/ad via one extra
// MFMA per A-frag against the precomputed w_asd fragment; stored from the
// accumulator with LOG2E fold.  C8: C stored as fp8 e4m3 (byte/lane).
#define BK 32

template <bool AF32, int WAVES_N, bool C8>
__global__ __launch_bounds__(256) void gemm_bf16(const void* __restrict__ Av,
                                                 const unsigned short* __restrict__ Bt,
                                                 const unsigned short* __restrict__ Wasd,
                                                 void* __restrict__ Cv,
                                                 float* __restrict__ as_o,
                                                 float* __restrict__ ad_o,
                                                 int M, int N, int K, int H) {
    constexpr int BMt = (4 / WAVES_N) * 64;
    constexpr int BNt = WAVES_N * 64;
    constexpr int ASLOTS = BMt * 4;               // 16B slots for the A tile
    constexpr int ROUNDS = (BMt + BNt) / 64;      // g2lds rounds (non-AF32)
    constexpr bool ASD_ALL = (WAVES_N == 1);
    __shared__ unsigned short As[2][BMt * BK];
    __shared__ unsigned short Bs[2][BNt * BK];
    __shared__ unsigned short Ws[2][16 * BK];
    int t = threadIdx.x;
    int bm = blockIdx.y * BMt;
    int wave = t >> 6, lane = t & 63;
    int wm = (wave / WAVES_N) * 64, wn = (wave % WAVES_N) * 64;
    int quad = lane >> 4, mr = lane & 15;

    f32x4 zero = {0.f, 0.f, 0.f, 0.f};
    f32x4 acc[4][4];
#pragma unroll
    for (int i = 0; i < 4; ++i)
#pragma unroll
        for (int j = 0; j < 4; ++j) acc[i][j] = zero;
    f32x4 acc4[4];
#pragma unroll
    for (int i = 0; i < 4; ++i) acc4[i] = zero;

    int sw = quad ^ ((mr >> 1) & 3);
    int aoff[4], boff[4];
#pragma unroll
    for (int i = 0; i < 4; ++i) {
        aoff[i] = (wm + i * 16 + mr) * BK + sw * 8;
        boff[i] = (wn + i * 16 + mr) * BK + sw * 8;
    }

    auto stage_ab = [&](int bsel, int kk) {
        const unsigned short* Ab = (const unsigned short*)Av;
#pragma unroll
        for (int r = 0; r < ROUNDS; ++r) {
            int slotw = r * 256 + wave * 64;      // wave-uniform slot base
            int slot = slotw + lane;
            if (slotw < ASLOTS) {
                int row = slot >> 2;
                int sg = (slot & 3) ^ ((row >> 1) & 3);
                int gra = bm + row;
                if (gra < M)
                    g2lds16(&Ab[(size_t)gra * K + kk + sg * 8], &As[bsel][slotw * 8]);
            } else {
                int bslot = slot - ASLOTS;
                int row = bslot >> 2;
                int sg = (bslot & 3) ^ ((row >> 1) & 3);
                g2lds16(&Bt[(size_t)row * K + kk + sg * 8], &Bs[bsel][(slotw - ASLOTS) * 8]);
            }
        }
        if (wave == 0)
            g2lds16(&Wasd[(size_t)(lane >> 2) * K + kk + (lane & 3) * 8], &Ws[bsel][0]);
    };
    auto stage_b_af32 = [&](int bsel, int kk) {
#pragma unroll
        for (int r = 0; r < BNt / 64; ++r) {
            int slotw = r * 256 + wave * 64;
            int bslot = slotw + lane;
            int row = bslot >> 2;
            int sg = (bslot & 3) ^ ((row >> 1) & 3);
            g2lds16(&Bt[(size_t)row * K + kk + sg * 8], &Bs[bsel][slotw * 8]);
        }
        if (wave == 0)
            g2lds16(&Wasd[(size_t)(lane >> 2) * K + kk + (lane & 3) * 8], &Ws[bsel][0]);
    };
    auto loadA_f32 = [&](int kk, float4& lo, float4& hi) {
        int slot = t, row = slot >> 2;
        int sg = (slot & 3) ^ ((row >> 1) & 3);
        int gra = bm + row;
        lo = make_float4(0.f, 0.f, 0.f, 0.f); hi = lo;
        if (gra < M) {
            const float* Af = (const float*)Av;
            lo = *(const float4*)&Af[(size_t)gra * K + kk + sg * 8];
            hi = *(const float4*)&Af[(size_t)gra * K + kk + sg * 8 + 4];
        }
    };
    auto writeA = [&](int bsel, float4 lo, float4 hi) {
        int slot = t;
        *(ushort4*)&As[bsel][slot * 8]     = make_ushort4(f2bf(lo.x), f2bf(lo.y), f2bf(lo.z), f2bf(lo.w));
        *(ushort4*)&As[bsel][slot * 8 + 4] = make_ushort4(f2bf(hi.x), f2bf(hi.y), f2bf(hi.z), f2bf(hi.w));
    };

    const int nt = K / BK;
    int cur = 0;

    if (AF32) {
        float4 l0, h0;
        loadA_f32(0, l0, h0);
        writeA(0, l0, h0);
        stage_b_af32(0, 0);
    } else {
        stage_ab(0, 0);
    }
    __syncthreads();

    for (int ts = 0; ts < nt; ++ts) {
        int nxt = cur ^ 1;
        bool more = (ts + 1 < nt);
        float4 plo, phi;
        if (more) {
            if (AF32) {
                loadA_f32((ts + 1) * BK, plo, phi);      // issue early
                stage_b_af32(nxt, (ts + 1) * BK);
            } else {
                stage_ab(nxt, (ts + 1) * BK);
            }
        }
        bf16x8 af[4], bfr[4];
#pragma unroll
        for (int i = 0; i < 4; ++i) {
            af[i]  = *(bf16x8*)&As[cur][aoff[i]];
            bfr[i] = *(bf16x8*)&Bs[cur][boff[i]];
        }
#pragma unroll
        for (int i = 0; i < 4; ++i)
#pragma unroll
            for (int j = 0; j < 4; ++j)
                acc[i][j] = __builtin_amdgcn_mfma_f32_16x16x32_bf16(af[i], bfr[j], acc[i][j], 0, 0, 0);
        if (ASD_ALL || wave == 0) {
            bf16x8 wsf = *(bf16x8*)&Ws[cur][mr * BK + quad * 8];
#pragma unroll
            for (int i = 0; i < 4; ++i)
                acc4[i] = __builtin_amdgcn_mfma_f32_16x16x32_bf16(af[i], wsf, acc4[i], 0, 0, 0);
        }
        if (more && AF32) writeA(nxt, plo, phi);         // write late
        __syncthreads();
        cur = nxt;
    }

    // as/ad store: D col=mr is coefficient index p (p<H: as, else ad)
    if ((ASD_ALL || wave == 0) && mr < 2 * H) {
#pragma unroll
        for (int i = 0; i < 4; ++i)
#pragma unroll
            for (int r = 0; r < 4; ++r) {
                int grow = bm + wm + i * 16 + quad * 4 + r;
                if (grow >= M) continue;
                float v = acc4[i][r] * LOG2E;
                if (mr < H) as_o[(size_t)grow * H + mr] = v;
                else        ad_o[(size_t)grow * H + (mr - H)] = v;
            }
    }

    // C store: C/D layout col=lane&15, row=quad*4+reg
#pragma unroll
    for (int i = 0; i < 4; ++i) {
#pragma unroll
        for (int r = 0; r < 4; ++r) {
            int grow = bm + wm + i * 16 + quad * 4 + r;
            if (grow >= M) continue;
#pragma unroll
            for (int j = 0; j < 4; ++j) {
                int gcol = wn + j * 16 + mr;
                if constexpr (C8) {
                    ((unsigned char*)Cv)[(size_t)grow * N + gcol] = f2fp8(acc[i][j][r]);
                } else {
                    ((unsigned short*)Cv)[(size_t)grow * N + gcol] = f2bf(acc[i][j][r]);
                }
            }
        }
    }
}

// ============================ aggregation ==================================
// Single-pass unnormalized softmax: out = sum(exp(e)*h) / (sum(exp(e))+eps).
// as/ad pre-scaled by log2(e) -> exp2; leaky = fmax(e, 0.2e).
// IN8 VPL=8: NPW=2, uint2 8B/lane; f32x2 accumulate -> v_pk_fma_f32.
// rowptr is ABSOLUTE — no chunk-offset gathers.
template <int H, int NPW, int VPL, bool OUTF32, bool IN8>
__global__ __launch_bounds__(256) void gat_aggregate(const void* __restrict__ hbuf_v,
                                                     const float* __restrict__ as_i,
                                                     const float* __restrict__ ad_i,
                                                     const int* __restrict__ rowptr,
                                                     const int* __restrict__ srcs,
                                                     const float* __restrict__ bias,
                                                     void* __restrict__ out_v, int N) {
    constexpr int LPN = 64 / NPW;        // lanes per node
    constexpr int HC = LPN * VPL;        // channels per node
    int wid = (blockIdx.x * blockDim.x + threadIdx.x) >> 6;
    int lane = threadIdx.x & 63;
    int sub = lane / LPN;                // which node within the wave
    int li  = lane % LPN;                // lane within node
    int node = wid * NPW + sub;
    if (node >= N) return;
    int row = rowptr[node];
    int end = rowptr[node + 1];
    int len = end - row;
    const int hd_lane = (li * VPL) >> 6; // head = channel/64

    float advh = ad_i[(size_t)node * H + hd_lane];

    float acc[VPL] __attribute__((aligned(16)));
#pragma unroll
    for (int j = 0; j < VPL; ++j) acc[j] = 0.f;
    float l = 0.f;

    const int U = 8;
    for (int base = 0; base < len; base += U) {
        int s[U];
        float cf[U];
#pragma unroll
        for (int u = 0; u < U; ++u) {
            int idx = base + u;
            int ii = row + ((idx < len) ? idx : (len - 1));
            s[u] = srcs[ii];
        }
#pragma unroll
        for (int u = 0; u < U; ++u) cf[u] = as_i[(size_t)s[u] * H + hd_lane];
        if constexpr (IN8 && VPL == 8) {
            // fp8 path: 8 channels = 8 bytes per edge-lane (uint2);
            // f32x2 accumulate -> v_pk_fma_f32
            const unsigned char* hb = (const unsigned char*)hbuf_v;
            uint2 r[U];
#pragma unroll
            for (int u = 0; u < U; ++u)
                r[u] = *(const uint2*)&hb[(size_t)s[u] * HC + li * VPL];
            f32x2* acc2 = (f32x2*)acc;
#pragma unroll
            for (int u = 0; u < U; ++u) {
                float e = cf[u] + advh;
                e = fmaxf(e, 0.2f * e);
                float wgt = (base + u < len) ? exp2f(e) : 0.f;
                l += wgt;
                f32x2 w2 = {wgt, wgt};
                acc2[0] += w2 * fp8pair<false>(r[u].x);
                acc2[1] += w2 * fp8pair<true >(r[u].x);
                acc2[2] += w2 * fp8pair<false>(r[u].y);
                acc2[3] += w2 * fp8pair<true >(r[u].y);
            }
        } else if constexpr (VPL == 8) {
            const unsigned short* hb = (const unsigned short*)hbuf_v;
            u16x8 r[U];
#pragma unroll
            for (int u = 0; u < U; ++u)
                r[u] = *(const u16x8*)&hb[(size_t)s[u] * HC + li * 8];
#pragma unroll
            for (int u = 0; u < U; ++u) {
                float e = cf[u] + advh;
                e = fmaxf(e, 0.2f * e);
                float wgt = (base + u < len) ? exp2f(e) : 0.f;
                l += wgt;
#pragma unroll
                for (int j = 0; j < 8; ++j) acc[j] += wgt * bf2f(r[u][j]);
            }
        } else {
            const unsigned short* hb = (const unsigned short*)hbuf_v;
            ushort4 r[U];
#pragma unroll
            for (int u = 0; u < U; ++u)
                r[u] = *(const ushort4*)&hb[(size_t)s[u] * HC + li * 4];
#pragma unroll
            for (int u = 0; u < U; ++u) {
                float e = cf[u] + advh;
                e = fmaxf(e, 0.2f * e);
                float wgt = (base + u < len) ? exp2f(e) : 0.f;
                l += wgt;
                acc[0] += wgt * bf2f(r[u].x);
                acc[1] += wgt * bf2f(r[u].y);
                acc[2] += wgt * bf2f(r[u].z);
                acc[3] += wgt * bf2f(r[u].w);
            }
        }
    }

    float inv_l = 1.f / (l + 1e-16f);
    float vals[VPL];
#pragma unroll
    for (int j = 0; j < VPL; ++j) {
        float v = acc[j] * inv_l + bias[li * VPL + j];
        vals[j] = (v > 0.f) ? v : (__expf(v) - 1.f);
    }
    if constexpr (OUTF32) {
        float* out = (float*)out_v;
        if constexpr (VPL == 4) {
            float4 o = make_float4(vals[0], vals[1], vals[2], vals[3]);
            *(float4*)&out[(size_t)node * HC + li * 4] = o;
        } else {
#pragma unroll
            for (int j = 0; j < VPL; ++j)
                out[(size_t)node * HC + li * VPL + j] = vals[j];
        }
    } else {
        unsigned short* out = (unsigned short*)out_v;
        if constexpr (VPL == 8) {
            u16x8 o;
#pragma unroll
            for (int j = 0; j < 8; ++j) o[j] = f2bf(vals[j]);
            *(u16x8*)&out[(size_t)node * HC + li * 8] = o;
        } else {
            ushort4 o;
            o.x = f2bf(vals[0]); o.y = f2bf(vals[1]);
            o.z = f2bf(vals[2]); o.w = f2bf(vals[3]);
            *(ushort4*)&out[(size_t)node * HC + li * 4] = o;
        }
    }
}

// ============================ pool + classify ==============================
#define POOL_CHUNK 128
__global__ __launch_bounds__(256) void pool_kernel(const float* __restrict__ hf,
                                                   const int* __restrict__ batch,
                                                   float* __restrict__ sums,
                                                   float* __restrict__ counts, int N) {
    int t = threadIdx.x;
    int c = t & 63, sub = t >> 6;
    int start = blockIdx.x * POOL_CHUNK;
    int end = min(start + POOL_CHUNK, N);
    float acc = 0.f, cnt = 0.f;
    int cur = -1;
    for (int n = start + sub; n < end; n += 4) {
        int g = batch[n];
        if (g != cur) {
            if (cur >= 0) {
                atomicAdd(&sums[cur * 64 + c], acc);
                if (c == 0) atomicAdd(&counts[cur], cnt);
            }
            cur = g; acc = 0.f; cnt = 0.f;
        }
        acc += hf[(size_t)n * 64 + c];
        cnt += 1.f;
    }
    if (cur >= 0) {
        atomicAdd(&sums[cur * 64 + c], acc);
        if (c == 0) atomicAdd(&counts[cur], cnt);
    }
}

__global__ void classify(const float* __restrict__ sums, const float* __restrict__ counts,
                         const float* __restrict__ Wc, const float* __restrict__ bc,
                         float* __restrict__ out, int NC) {
    __shared__ float p[64];
    int g = blockIdx.x;
    if (threadIdx.x < 64) {
        float cnt = fmaxf(counts[g], 1.0f);
        p[threadIdx.x] = sums[g * 64 + threadIdx.x] / cnt;
    }
    __syncthreads();
    int k = threadIdx.x;
    if (k < NC) {
        float acc = bc[k];
        for (int c = 0; c < 64; ++c) acc += p[c] * Wc[c * NC + k];
        out[g * NC + k] = acc;
    }
}

static inline size_t align_up(size_t x, size_t a) { return (x + a - 1) / a * a; }

extern "C" void kernel_launch(void* const* d_in, const int* in_sizes, int n_in,
                              void* d_out, int out_size, void* d_ws, size_t ws_size,
                              hipStream_t stream) {
    const float* x      = (const float*)d_in[0];
    const int*   ei     = (const int*)d_in[1];
    const int*   batch  = (const int*)d_in[2];
    const float* W1     = (const float*)d_in[3];
    const float* a_src1 = (const float*)d_in[4];
    const float* a_dst1 = (const float*)d_in[5];
    const float* b1     = (const float*)d_in[6];
    const float* W2     = (const float*)d_in[7];
    const float* a_src2 = (const float*)d_in[8];
    const float* a_dst2 = (const float*)d_in[9];
    const float* b2     = (const float*)d_in[10];
    const float* W3     = (const float*)d_in[11];
    const float* a_src3 = (const float*)d_in[12];
    const float* a_dst3 = (const float*)d_in[13];
    const float* b3     = (const float*)d_in[14];
    const float* Wc     = (const float*)d_in[15];
    const float* bc     = (const float*)d_in[16];

    const int N    = in_sizes[2];
    const int E    = in_sizes[1] / 2;
    const int F_IN = in_sizes[0] / N;   // 128
    const int HC   = in_sizes[6];       // 256
    const int C    = in_sizes[14];      // 64
    const int NC   = in_sizes[16];      // 200
    const int Etot = E + N;
    const int NB   = (N + 1023) / 1024;
    const int NPB  = (N + POOL_CHUNK - 1) / POOL_CHUNK;

    char* w = (char*)d_ws;
    size_t off = 0;
    auto alloc = [&](size_t bytes) -> void* {
        void* p = w + off;
        off = align_up(off + bytes, 256);
        return p;
    };
    int*   deg    = (int*)alloc((size_t)N * 4);
    // sums + counts in one prep-zeroed region
    float* sums   = (float*)alloc((size_t)(64 * 64 + 64) * 4);
    float* counts = sums + 64 * 64;
    int*   rowptr = (int*)alloc((size_t)(N + 1) * 4);
    int*   epos   = (int*)alloc((size_t)E * 4);
    int*   srcs   = (int*)alloc((size_t)Etot * 4);
    int*   aggst  = (int*)alloc((size_t)(NB + 1) * 4);
    float* as_buf = (float*)alloc((size_t)N * 4 * 4);
    float* ad_buf = (float*)alloc((size_t)N * 4 * 4);
    unsigned short* Wt1 = (unsigned short*)alloc((size_t)HC * F_IN * 2);
    unsigned short* Wt2 = (unsigned short*)alloc((size_t)HC * HC * 2);
    unsigned short* Wt3 = (unsigned short*)alloc((size_t)C * HC * 2);
    unsigned short* wasd1 = (unsigned short*)alloc((size_t)16 * F_IN * 2);
    unsigned short* wasd2 = (unsigned short*)alloc((size_t)16 * HC * 2);
    unsigned short* wasd3 = (unsigned short*)alloc((size_t)16 * HC * 2);
    unsigned char*  hA  = (unsigned char*)alloc((size_t)N * HC);      // fp8 h-table
    unsigned short* hB  = (unsigned short*)alloc((size_t)N * HC * 2); // bf16 agg out
    unsigned short* hC  = (unsigned short*)alloc((size_t)N * C * 2);
    float* bufF   = (float*)alloc((size_t)N * C * 4);

    const int TPB = 256;

    // ---- weight casts + w_asd + zeroing (deg/sums) + scan arming ----
    int n1 = HC * F_IN, n2 = HC * HC, n3 = C * HC;
    int ntot = n1 + n2 + n3 + 16 * F_IN + 16 * HC + 16 * HC;
    int zn = 64 * 64 + 64;
    int gPrep = (max(ntot, N) + TPB - 1) / TPB;
    prep_weights<<<gPrep, TPB, 0, stream>>>(
        W1, Wt1, W2, Wt2, W3, Wt3,
        a_src1, a_dst1, a_src2, a_dst2, a_src3, a_dst3,
        wasd1, wasd2, wasd3, deg, sums, aggst, N, zn, NB, n1, n2, n3, F_IN, HC, C);

    // ---- CSR build: count -> fused lookback scan -> scatter ----
    count_edges<<<(E + TPB - 1) / TPB, TPB, 0, stream>>>(ei, deg, epos, E);
    scan_fused<<<NB, 256, 0, stream>>>(deg, rowptr, aggst, N, NB);
    scatter_edges<<<(Etot + TPB - 1) / TPB, TPB, 0, stream>>>(ei, rowptr, deg, epos, srcs, E, N);

    dim3 gWide(1, (N + 63) / 64);        // BM=64 x BN=256
    dim3 gNarrow(1, (N + 255) / 256);    // BM=256 x BN=64
    int aggBlocks12 = (N + 7) / 8;               // NPW=2: 8 nodes/block
    int aggBlocks3  = (((N + 3) / 4) + 3) / 4;   // NPW=4

    // ---- Layer 1 (A = f32 x, converted in staging; C -> fp8 hA) ----
    gemm_bf16<true, 4, true><<<gWide, 256, 0, stream>>>(x, Wt1, wasd1, hA, as_buf, ad_buf, N, HC, F_IN, 4);
    gat_aggregate<4, 2, 8, false, true><<<aggBlocks12, 256, 0, stream>>>(hA, as_buf, ad_buf, rowptr, srcs, b1, hB, N);

    // ---- Layer 2 (A = bf16 hB; C -> fp8 hA) ----
    gemm_bf16<false, 4, true><<<gWide, 256, 0, stream>>>(hB, Wt2, wasd2, hA, as_buf, ad_buf, N, HC, HC, 4);
    gat_aggregate<4, 2, 8, false, true><<<aggBlocks12, 256, 0, stream>>>(hA, as_buf, ad_buf, rowptr, srcs, b2, hB, N);

    // ---- Layer 3 (H=1; bf16 throughout) ----
    gemm_bf16<false, 1, false><<<gNarrow, 256, 0, stream>>>(hB, Wt3, wasd3, hC, as_buf, ad_buf, N, C, HC, 1);
    gat_aggregate<1, 4, 4, true, false><<<aggBlocks3, 256, 0, stream>>>(hC, as_buf, ad_buf, rowptr, srcs, b3, bufF, N);

    // ---- Pool + classify (separate, high-occupancy, proven) ----
    pool_kernel<<<NPB, 256, 0, stream>>>(bufF, batch, sums, counts, N);
    classify<<<64, 256, 0, stream>>>(sums, counts, Wc, bc, (float*)d_out, NC);
}